// Round 5
// baseline (8905.787 us; speedup 1.0000x reference)
//
#include <hip/hip_runtime.h>
#include <cmath>

#define Bsz 128
#define Ssz 512
#define Isz 512
#define Hsz 1024
#define G4  4096
#define Ktot 1536   // I + H
#define NT  32      // col-tiles of 128 perm-cols (32 hidden units)
#define KT  8       // K-slices of 192
#define KSL 192

typedef short s8v __attribute__((ext_vector_type(8)));        // 8 bf16 (4 VGPRs)
typedef unsigned short u16x8 __attribute__((ext_vector_type(8)));
typedef float f32x16 __attribute__((ext_vector_type(16)));
typedef float f32x4  __attribute__((ext_vector_type(4)));

__device__ __forceinline__ unsigned short f2bf(float f) {
    unsigned u = __float_as_uint(f);
    u += 0x7fffu + ((u >> 16) & 1u);
    return (unsigned short)(u >> 16);
}
__device__ __forceinline__ float bf2f(unsigned short h) {
    return __uint_as_float(((unsigned)h) << 16);
}
__device__ __forceinline__ float fsig(float v) { return 1.f / (1.f + __expf(-v)); }
__device__ __forceinline__ float ftanh(float v) { return 2.f / (1.f + __expf(-2.f * v)) - 1.f; }

// ---- once per call: W,U -> transposed bf16 hi/lo planes, GATE-INTERLEAVED columns.
// dst row for orig column n (n = g*1024 + j): perm(n) = j*4 + g.
__global__ __launch_bounds__(256) void conv_wu(const float* __restrict__ W,
                                               const float* __restrict__ U,
                                               unsigned short* __restrict__ WUthi,
                                               unsigned short* __restrict__ WUtlo) {
    __shared__ float tile[32][33];
    const int tx = threadIdx.x & 31, ty = threadIdx.x >> 5;
    const int nb = blockIdx.x * 32, kb = blockIdx.y * 32;
    #pragma unroll
    for (int r = 0; r < 4; ++r) {
        int k = kb + ty + r * 8;
        float v = (k < Isz) ? W[(size_t)k * G4 + nb + tx]
                            : U[(size_t)(k - Isz) * G4 + nb + tx];
        tile[ty + r * 8][tx] = v;
    }
    __syncthreads();
    #pragma unroll
    for (int r = 0; r < 4; ++r) {
        int nl = ty + r * 8;
        int n  = nb + nl;                        // orig column (tile never straddles a gate)
        int pn = ((n & 1023) << 2) | (n >> 10);  // j*4 + g
        float v = tile[tx][nl];
        unsigned short h = f2bf(v);
        size_t dst = (size_t)pn * Ktot + kb + tx;
        WUthi[dst] = h;
        WUtlo[dst] = f2bf(v - bf2f(h));
    }
}

// ---- once per call: zero h0/counters, permute bias, split x[:,0,:]
__global__ __launch_bounds__(256) void lstm_init(const float* __restrict__ x,
                                                 const float* __restrict__ bias,
                                                 unsigned short* __restrict__ hhi0, unsigned short* __restrict__ hlo0,
                                                 unsigned short* __restrict__ xthi0, unsigned short* __restrict__ xtlo0,
                                                 float* __restrict__ biasP, unsigned* __restrict__ cnt) {
    int idx = blockIdx.x * 256 + threadIdx.x;   // 131072 threads
    hhi0[idx] = 0; hlo0[idx] = 0;
    if (idx < Bsz * Isz) {
        int b = idx >> 9, i = idx & 511;
        float xv = x[(size_t)b * Ssz * Isz + i];   // t = 0
        unsigned short h = f2bf(xv);
        xthi0[idx] = h;
        xtlo0[idx] = f2bf(xv - bf2f(h));
    }
    if (idx < G4)   biasP[idx] = bias[((idx & 3) << 10) | (idx >> 2)];  // biasP[j*4+g]
    if (idx < 2048) cnt[idx] = 0u;
}

// ---- PERSISTENT weight-stationary kernel: all 512 steps in one launch.
// grid = 256 blocks (1/CU, forced by 147.5 KB LDS): nt = bid&31, kt = bid>>5.
// B tile (hi+lo, 3 K-chunk slabs) resident in LDS for the whole kernel.
// Cross-block data (h, x-split, P) via sc0 sc1 (LLC-level) stores/loads — proven R4.
// Sync: group-of-8 ticket for P, full-grid LLC spin barrier per step (NOT grid.sync).
#define PITCH 72                      // 64 k + 8 pad (u16); 144 B rows, 16B-aligned
#define SLAB  (128 * PITCH)           // 9216 u16 = one 128-row x 64-k slab
#define SMEM_ELEMS (8 * SLAB)         // Bhi[3] Blo[3] Ahi Alo = 73728 u16 = 147456 B

#define GLOAD16(dst, ptr) \
    asm volatile("global_load_dwordx4 %0, %1, off sc0 sc1" : "=v"(dst) : "v"(ptr))

__global__ __launch_bounds__(512) void lstm_persist(
    const unsigned short* __restrict__ WUthi, const unsigned short* __restrict__ WUtlo,
    const float* __restrict__ xin, const float* __restrict__ biasP,
    float* __restrict__ P,
    unsigned short* __restrict__ xh0, unsigned short* __restrict__ xl0,
    unsigned short* __restrict__ xh1, unsigned short* __restrict__ xl1,
    unsigned short* __restrict__ hh0, unsigned short* __restrict__ hl0,
    unsigned short* __restrict__ hh1, unsigned short* __restrict__ hl1,
    unsigned* __restrict__ cnt, float* __restrict__ out) {
    extern __shared__ unsigned short sm[];
    unsigned short* sBhi = sm;                 // 3 slabs
    unsigned short* sBlo = sm + 3 * SLAB;      // 3 slabs
    unsigned short* sAhi = sm + 6 * SLAB;      // 1 slab (single-buffered, reg-prefetch)
    unsigned short* sAlo = sm + 7 * SLAB;

    const int tid = threadIdx.x, lane = tid & 63, w = tid >> 6;
    const int bid = blockIdx.x;
    const int nt = bid & 31, kt = bid >> 5;
    const int ktK = kt * KSL;

    // ---- B tile -> LDS once (normal cached loads; weights never reloaded again)
    #pragma unroll
    for (int i = 0; i < 6; ++i) {
        int q = i * 512 + tid;                 // 3072 slots
        int kcB = q >> 10, rr = (q >> 3) & 127, oct = q & 7;
        size_t src = (size_t)(nt * 128 + rr) * Ktot + ktK + kcB * 64 + oct * 8;
        *(u16x8*)&sBhi[kcB * SLAB + rr * PITCH + oct * 8] = *(const u16x8*)&WUthi[src];
        *(u16x8*)&sBlo[kcB * SLAB + rr * PITCH + oct * 8] = *(const u16x8*)&WUtlo[src];
    }

    const int m31  = lane & 31;
    const int koct = (lane >> 5) << 3;         // 0 or 8
    const int mq = w & 3, nh = w >> 2;         // 8 waves: 4 M-tiles x 2 col-pairs
    const int rowA  = (mq * 32 + m31) * PITCH + koct;
    const int rowB0 = (nh * 64 + m31) * PITCH + koct;
    const int rowB1 = rowB0 + 32 * PITCH;
    const int arow = tid >> 3, aoct = tid & 7; // staging: rows arow, arow+64
    const int awr0 = arow * PITCH + aoct * 8;
    const int awr1 = awr0 + 64 * PITCH;

    // ---- fixed pointwise ownership: this thread owns (brow, j) forever
    const int brow = kt * 16 + (tid >> 5);     // batch row
    const int jl = tid & 31;
    const int j = nt * 32 + jl;                // hidden unit
    float c_reg = 0.f, hs_reg = 0.f;
    const f32x4 bp = *(const f32x4*)&biasP[4 * j];

    __syncthreads();                           // B resident

    f32x4 rAh0, rAl0, rAh1, rAl1;
#define LOADA(KC) { \
        const int kb_ = ktK + (KC) * 64; \
        const int kg_ = kb_ + aoct * 8; \
        if (kb_ < Isz) { \
            const unsigned short* p0h = xhr + (size_t)arow * Isz + kg_; \
            const unsigned short* p0l = xlr + (size_t)arow * Isz + kg_; \
            GLOAD16(rAh0, p0h); GLOAD16(rAl0, p0l); \
            GLOAD16(rAh1, p0h + (size_t)64 * Isz); GLOAD16(rAl1, p0l + (size_t)64 * Isz); \
        } else { \
            const unsigned short* p0h = hhr + (size_t)arow * Hsz + (kg_ - Isz); \
            const unsigned short* p0l = hlr + (size_t)arow * Hsz + (kg_ - Isz); \
            GLOAD16(rAh0, p0h); GLOAD16(rAl0, p0l); \
            GLOAD16(rAh1, p0h + (size_t)64 * Hsz); GLOAD16(rAl1, p0l + (size_t)64 * Hsz); \
        } }

    #pragma unroll 1
    for (int t = 0; t < Ssz; ++t) {
        const unsigned short* xhr = (t & 1) ? xh1 : xh0;
        const unsigned short* xlr = (t & 1) ? xl1 : xl0;
        const unsigned short* hhr = (t & 1) ? hh1 : hh0;
        const unsigned short* hlr = (t & 1) ? hl1 : hl0;
        unsigned short* xhw = (t & 1) ? xh0 : xh1;
        unsigned short* xlw = (t & 1) ? xl0 : xl1;
        unsigned short* hhw = (t & 1) ? hh0 : hh1;
        unsigned short* hlw = (t & 1) ? hl0 : hl1;

        f32x16 acc0, acc1;
        #pragma unroll
        for (int i = 0; i < 16; ++i) { acc0[i] = 0.f; acc1[i] = 0.f; }

        LOADA(0);
        #pragma unroll
        for (int kc = 0; kc < 3; ++kc) {       // 3 chunks of K=64 (slice 192)
            __syncthreads();                   // A slab free
            asm volatile("s_waitcnt vmcnt(0)" ::: "memory");   // A regs arrived
            *(f32x4*)&sAhi[awr0] = rAh0;
            *(f32x4*)&sAlo[awr0] = rAl0;
            *(f32x4*)&sAhi[awr1] = rAh1;
            *(f32x4*)&sAlo[awr1] = rAl1;
            if (kc < 2) LOADA(kc + 1);         // next chunk flies under MFMA
            __syncthreads();
            const int sb = kc * SLAB;
            #pragma unroll
            for (int s = 0; s < 4; ++s) {      // 4x K16
                const int o = s * 16;
                s8v ah  = *(const s8v*)&sAhi[rowA + o];
                s8v al  = *(const s8v*)&sAlo[rowA + o];
                s8v b0h = *(const s8v*)&sBhi[sb + rowB0 + o];
                s8v b0l = *(const s8v*)&sBlo[sb + rowB0 + o];
                s8v b1h = *(const s8v*)&sBhi[sb + rowB1 + o];
                s8v b1l = *(const s8v*)&sBlo[sb + rowB1 + o];
                acc0 = __builtin_amdgcn_mfma_f32_32x32x16_bf16(ah, b0h, acc0, 0, 0, 0);
                acc1 = __builtin_amdgcn_mfma_f32_32x32x16_bf16(ah, b1h, acc1, 0, 0, 0);
                acc0 = __builtin_amdgcn_mfma_f32_32x32x16_bf16(al, b0h, acc0, 0, 0, 0);
                acc1 = __builtin_amdgcn_mfma_f32_32x32x16_bf16(al, b1h, acc1, 0, 0, 0);
                acc0 = __builtin_amdgcn_mfma_f32_32x32x16_bf16(ah, b0l, acc0, 0, 0, 0);
                acc1 = __builtin_amdgcn_mfma_f32_32x32x16_bf16(ah, b1l, acc1, 0, 0, 0);
            }
        }

        // ---- P partial store, LLC-level. C/D layout (m74/m101):
        // col = lane&31, row = (reg&3) + 8*(reg>>2) + 4*(lane>>5)
        {
            float* Ps = P + (size_t)(kt * NT + nt) * (Bsz * 128);
            const int mb = mq * 32 + 4 * (lane >> 5);
            const int c0 = nh * 64 + m31;
            #pragma unroll
            for (int r = 0; r < 16; ++r) {
                int m = mb + (r & 3) + 8 * (r >> 2);
                float* p0 = Ps + m * 128 + c0;
                asm volatile("global_store_dword %0, %1, off sc0 sc1" :: "v"(p0), "v"(acc0[r]) : "memory");
                asm volatile("global_store_dword %0, %1, off sc0 sc1" :: "v"(p0 + 32), "v"(acc1[r]) : "memory");
            }
        }
        asm volatile("s_waitcnt vmcnt(0)" ::: "memory");
        __syncthreads();                       // all waves' P drained

        // ---- stage next x slice (overlaps ticket spin; drained before full barrier)
        if (t + 1 < Ssz && tid < 256) {
            int idx = bid * 256 + tid;         // 256 blocks x 256 = 65536 elems
            int bb = idx >> 9, ii = idx & 511;
            float xv = xin[((size_t)bb * Ssz + (t + 1)) * Isz + ii];
            unsigned short xh_ = f2bf(xv);
            unsigned short xl_ = f2bf(xv - bf2f(xh_));
            unsigned short* pxh = &xhw[idx];
            unsigned short* pxl = &xlw[idx];
            asm volatile("global_store_short %0, %1, off sc0 sc1" :: "v"(pxh), "v"((unsigned)xh_) : "memory");
            asm volatile("global_store_short %0, %1, off sc0 sc1" :: "v"(pxl), "v"((unsigned)xl_) : "memory");
        }

        // ---- ticket: wait until all 8 kt-blocks of this nt stored P (cumulative)
        if (tid == 0) {
            unsigned* cp = &cnt[nt * 32];
            asm volatile("global_atomic_add %0, %1, off sc1" :: "v"(cp), "v"(1u) : "memory");
            const unsigned target = 8u * (unsigned)(t + 1);
            unsigned v;
            do {
                __builtin_amdgcn_s_sleep(1);
                asm volatile("global_load_dword %0, %1, off sc0 sc1\n\ts_waitcnt vmcnt(0)"
                             : "=v"(v) : "v"(cp) : "memory");
            } while (v < target);
        }
        __syncthreads();

        // ---- reduce 8 partials + pointwise; c/hsum live in registers
        {
            const float* Pbase = P + (size_t)nt * (Bsz * 128) + brow * 128 + jl * 4;
            f32x4 pr[KT];
            #pragma unroll
            for (int k2 = 0; k2 < KT; ++k2) {
                const float* p_ = Pbase + (size_t)k2 * (NT * Bsz * 128);
                GLOAD16(pr[k2], p_);
            }
            asm volatile("s_waitcnt vmcnt(0)" ::: "memory");
            __builtin_amdgcn_sched_barrier(0);
            float gf = bp.x, gi = bp.y, gg = bp.z, go = bp.w;
            #pragma unroll
            for (int k2 = 0; k2 < KT; ++k2) {
                gf += pr[k2][0]; gi += pr[k2][1]; gg += pr[k2][2]; go += pr[k2][3];
            }
            float f  = fsig(gf);
            float i_ = fsig(gi);
            float g  = ftanh(gg);
            float o  = fsig(go);
            c_reg = f * c_reg + i_ * g;
            float hn = o * ftanh(c_reg);
            hs_reg += hn;
            unsigned short hh_ = f2bf(hn);
            unsigned short hl_ = f2bf(hn - bf2f(hh_));
            size_t sidx = (size_t)brow * Hsz + j;
            unsigned short* ph = &hhw[sidx];
            unsigned short* pl = &hlw[sidx];
            asm volatile("global_store_short %0, %1, off sc0 sc1" :: "v"(ph), "v"((unsigned)hh_) : "memory");
            asm volatile("global_store_short %0, %1, off sc0 sc1" :: "v"(pl), "v"((unsigned)hl_) : "memory");
        }

        // ---- full-grid LLC barrier: h(t+1)/x(t+1) visible before anyone starts t+1
        asm volatile("s_waitcnt vmcnt(0)" ::: "memory");
        __syncthreads();
        if (tid == 0) {
            unsigned* bpc = &cnt[1024];
            asm volatile("global_atomic_add %0, %1, off sc1" :: "v"(bpc), "v"(1u) : "memory");
            const unsigned target = 256u * (unsigned)(t + 1);
            unsigned v;
            do {
                __builtin_amdgcn_s_sleep(2);
                asm volatile("global_load_dword %0, %1, off sc0 sc1\n\ts_waitcnt vmcnt(0)"
                             : "=v"(v) : "v"(bpc) : "memory");
            } while (v < target);
        }
        __syncthreads();
    }
#undef LOADA

    out[(size_t)brow * Hsz + j] = hs_reg * (1.f / (float)Ssz);
}

extern "C" void kernel_launch(void* const* d_in, const int* in_sizes, int n_in,
                              void* d_out, int out_size, void* d_ws, size_t ws_size,
                              hipStream_t stream) {
    const float* x    = (const float*)d_in[0];
    const float* W    = (const float*)d_in[1];
    const float* U    = (const float*)d_in[2];
    const float* bias = (const float*)d_in[3];
    float* out = (float*)d_out;

    unsigned char* base = (unsigned char*)d_ws;
    // ws carve (~43.6 MB total)
    unsigned short* WUthi = (unsigned short*)(base);                       // 12,582,912 B
    unsigned short* WUtlo = (unsigned short*)(base + 12582912);            // 12,582,912 B
    float*          P     = (float*)(base + 25165824);                     // 16,777,216 B
    unsigned short* hh0   = (unsigned short*)(base + 41943040);            //    262,144 B
    unsigned short* hl0   = (unsigned short*)(base + 42205184);            //    262,144 B
    unsigned short* hh1   = (unsigned short*)(base + 42467328);            //    262,144 B
    unsigned short* hl1   = (unsigned short*)(base + 42729472);            //    262,144 B
    unsigned short* xh0   = (unsigned short*)(base + 42991616);            //    131,072 B
    unsigned short* xl0   = (unsigned short*)(base + 43122688);            //    131,072 B
    unsigned short* xh1   = (unsigned short*)(base + 43253760);            //    131,072 B
    unsigned short* xl1   = (unsigned short*)(base + 43384832);            //    131,072 B
    float*          biasP = (float*)(base + 43515904);                     //     16,384 B
    unsigned*       cnt   = (unsigned*)(base + 43532288);                  //      8,192 B

    static bool attr_done = false;
    if (!attr_done) {
        (void)hipFuncSetAttribute((const void*)lstm_persist,
                                  hipFuncAttributeMaxDynamicSharedMemorySize,
                                  SMEM_ELEMS * 2);
        attr_done = true;
    }

    conv_wu<<<dim3(G4 / 32, Ktot / 32), 256, 0, stream>>>(W, U, WUthi, WUtlo);
    lstm_init<<<(Bsz * Hsz) / 256, 256, 0, stream>>>(x, bias, hh0, hl0, xh0, xl0, biasP, cnt);

    lstm_persist<<<NT * KT, 512, SMEM_ELEMS * 2, stream>>>(
        WUthi, WUtlo, x, biasP, P,
        xh0, xl0, xh1, xl1, hh0, hl0, hh1, hl1, cnt, out);
}

// Round 6
// 6630.641 us; speedup vs baseline: 1.3431x; 1.3431x over previous
//
#include <hip/hip_runtime.h>
#include <cmath>

#define Bsz 128
#define Ssz 512
#define Isz 512
#define Hsz 1024
#define G4  4096
#define Ktot 1536   // I + H
#define NT  64      // N-tiles of 64 perm-cols (16 hidden units)
#define KT  4       // K-slices of 384
#define KSL 384

typedef short s8v __attribute__((ext_vector_type(8)));        // 8 bf16 (4 VGPRs)
typedef unsigned short u16x8 __attribute__((ext_vector_type(8)));
typedef float f32x16 __attribute__((ext_vector_type(16)));
typedef float f32x4  __attribute__((ext_vector_type(4)));

__device__ __forceinline__ unsigned short f2bf(float f) {
    unsigned u = __float_as_uint(f);
    u += 0x7fffu + ((u >> 16) & 1u);
    return (unsigned short)(u >> 16);
}
__device__ __forceinline__ float bf2f(unsigned short h) {
    return __uint_as_float(((unsigned)h) << 16);
}
__device__ __forceinline__ float fsig(float v) { return 1.f / (1.f + __expf(-v)); }
__device__ __forceinline__ float ftanh(float v) { return 2.f / (1.f + __expf(-2.f * v)) - 1.f; }

// ---- once per call: W,U -> transposed bf16 hi/lo planes, GATE-INTERLEAVED columns.
// dst row for orig column n (n = g*1024 + j): perm(n) = j*4 + g.
__global__ __launch_bounds__(256) void conv_wu(const float* __restrict__ W,
                                               const float* __restrict__ U,
                                               unsigned short* __restrict__ WUthi,
                                               unsigned short* __restrict__ WUtlo) {
    __shared__ float tile[32][33];
    const int tx = threadIdx.x & 31, ty = threadIdx.x >> 5;
    const int nb = blockIdx.x * 32, kb = blockIdx.y * 32;
    #pragma unroll
    for (int r = 0; r < 4; ++r) {
        int k = kb + ty + r * 8;
        float v = (k < Isz) ? W[(size_t)k * G4 + nb + tx]
                            : U[(size_t)(k - Isz) * G4 + nb + tx];
        tile[ty + r * 8][tx] = v;
    }
    __syncthreads();
    #pragma unroll
    for (int r = 0; r < 4; ++r) {
        int nl = ty + r * 8;
        int n  = nb + nl;                        // orig column (tile never straddles a gate)
        int pn = ((n & 1023) << 2) | (n >> 10);  // j*4 + g
        float v = tile[tx][nl];
        unsigned short h = f2bf(v);
        size_t dst = (size_t)pn * Ktot + kb + tx;
        WUthi[dst] = h;
        WUtlo[dst] = f2bf(v - bf2f(h));
    }
}

// ---- once per call: zero state/counters, permute bias, split x[:,0,:]
__global__ __launch_bounds__(256) void lstm_init(const float* __restrict__ x,
                                                 const float* __restrict__ bias,
                                                 float* __restrict__ c, float* __restrict__ hsum,
                                                 unsigned short* __restrict__ hhi0, unsigned short* __restrict__ hlo0,
                                                 unsigned short* __restrict__ xthi0, unsigned short* __restrict__ xtlo0,
                                                 float* __restrict__ biasP, unsigned* __restrict__ cnt) {
    int idx = blockIdx.x * 256 + threadIdx.x;   // 131072 threads
    c[idx] = 0.f; hsum[idx] = 0.f; hhi0[idx] = 0; hlo0[idx] = 0;
    if (idx < Bsz * Isz) {
        int b = idx >> 9, i = idx & 511;
        float xv = x[(size_t)b * Ssz * Isz + i];   // t = 0
        unsigned short h = f2bf(xv);
        xthi0[idx] = h;
        xtlo0[idx] = f2bf(xv - bf2f(h));
    }
    if (idx < G4)   biasP[idx] = bias[((idx & 3) << 10) | (idx >> 2)];  // biasP[j*4+g]
    if (idx < 2048) cnt[idx] = 0u;
}

// ---- per step, ONE kernel: split-K GEMM + spin-grouped fused pointwise.
// grid = 256 blocks: nt = bid&63 (64-col tile), kt = bid>>6 (K-slice of 384).
// P partials move at AGENT scope (sc1 = device/LLC), NOT system (sc0 sc1 = HBM):
// R5 counters showed sc0 sc1 costs 15 GB of HBM traffic (20% peak, the bottleneck).
// A/h/x loads stay normal (per-XCD L2-cached; kernel boundary gives coherence).
// Self-slice: rows [kt*32,kt*32+32) skip global P entirely (LDS bounce, wave mq==kt).
#define PITCH 72          // 64 k + 8 pad (u16 elems); 144 B, bank-uniform
#define A_HI 0
#define A_LO (128 * PITCH)
#define B_HI (2 * 128 * PITCH)
#define B_LO (2 * 128 * PITCH + 64 * PITCH)
#define SMEM_ELEMS (2 * 128 * PITCH + 2 * 64 * PITCH)   // 27648 u16 = 55296 B
#define LREDP 68          // self-slice float pitch (32 x 64 tile, 8704 B into A region)

#define GLOAD16_DEV(dst, ptr) \
    asm volatile("global_load_dwordx4 %0, %1, off sc1" : "=v"(dst) : "v"(ptr))

__global__ __launch_bounds__(512) void lstm_step(
    const unsigned short* __restrict__ WUthi, const unsigned short* __restrict__ WUtlo,
    const unsigned short* __restrict__ xthi,  const unsigned short* __restrict__ xtlo,
    const unsigned short* __restrict__ hhi_in, const unsigned short* __restrict__ hlo_in,
    const float* __restrict__ biasP, const float* __restrict__ x, int t,
    float* __restrict__ c_st, float* __restrict__ hsum,
    unsigned short* __restrict__ hhi_o, unsigned short* __restrict__ hlo_o,
    unsigned short* __restrict__ xthi_o, unsigned short* __restrict__ xtlo_o,
    float* __restrict__ P, unsigned* __restrict__ cnt,
    float* __restrict__ out) {
    extern __shared__ unsigned short sm[];
    unsigned short* sAhi = sm + A_HI;
    unsigned short* sAlo = sm + A_LO;
    unsigned short* sBhi = sm + B_HI;
    unsigned short* sBlo = sm + B_LO;

    const int tid = threadIdx.x, lane = tid & 63, w = tid >> 6;
    const int bid = blockIdx.x;
    const int nt = bid & 63, kt = bid >> 6;

    const int m31  = lane & 31;
    const int koct = (lane >> 5) << 3;                 // 0 or 8
    const int mq = w & 3, nh = w >> 2;                 // 8 waves = 4 mq x 2 nh, tile 32x32
    const int rowA = (mq * 32 + m31) * PITCH + koct;
    const int rowB = (nh * 32 + m31) * PITCH + koct;

    // staging slots: A rows arow & arow+64, B row arow (0..63); oct = aoct
    const int arow = tid >> 3, aoct = tid & 7;
    const int awr0 = arow * PITCH + aoct * 8;
    const int awr1 = (arow + 64) * PITCH + aoct * 8;

    f32x16 acc;
    #pragma unroll
    for (int i = 0; i < 16; ++i) acc[i] = 0.f;

    u16x8 rAh0, rAl0, rAh1, rAl1, rBh, rBl;
#define LOADCHUNK(KC) { \
        const int kb_ = kt * KSL + (KC) * 64; \
        const int kg_ = kb_ + aoct * 8; \
        if (kb_ < Isz) { \
            const size_t o0 = (size_t)arow * Isz + kg_, o1 = (size_t)(arow + 64) * Isz + kg_; \
            rAh0 = *(const u16x8*)&xthi[o0]; rAl0 = *(const u16x8*)&xtlo[o0]; \
            rAh1 = *(const u16x8*)&xthi[o1]; rAl1 = *(const u16x8*)&xtlo[o1]; \
        } else { \
            const size_t o0 = (size_t)arow * Hsz + (kg_ - Isz), o1 = (size_t)(arow + 64) * Hsz + (kg_ - Isz); \
            rAh0 = *(const u16x8*)&hhi_in[o0]; rAl0 = *(const u16x8*)&hlo_in[o0]; \
            rAh1 = *(const u16x8*)&hhi_in[o1]; rAl1 = *(const u16x8*)&hlo_in[o1]; \
        } \
        const size_t ob_ = (size_t)(nt * 64 + arow) * Ktot + kg_; \
        rBh = *(const u16x8*)&WUthi[ob_]; rBl = *(const u16x8*)&WUtlo[ob_]; \
    }

    LOADCHUNK(0);
    #pragma unroll
    for (int kc = 0; kc < 6; ++kc) {                   // 6 chunks of K=64 (slice K=384)
        __syncthreads();                               // LDS free (prev compute done)
        *(u16x8*)&sAhi[awr0] = rAh0;
        *(u16x8*)&sAlo[awr0] = rAl0;
        *(u16x8*)&sAhi[awr1] = rAh1;
        *(u16x8*)&sAlo[awr1] = rAl1;
        *(u16x8*)&sBhi[awr0] = rBh;
        *(u16x8*)&sBlo[awr0] = rBl;
        if (kc < 5) LOADCHUNK(kc + 1);                 // next-chunk loads fly under MFMA
        __syncthreads();
        #pragma unroll
        for (int s = 0; s < 4; ++s) {                  // 4x K16 per chunk
            const int o = s * 16;
            s8v ah = *(const s8v*)&sAhi[rowA + o];
            s8v al = *(const s8v*)&sAlo[rowA + o];
            s8v bh = *(const s8v*)&sBhi[rowB + o];
            s8v bl = *(const s8v*)&sBlo[rowB + o];
            acc = __builtin_amdgcn_mfma_f32_32x32x16_bf16(ah, bh, acc, 0, 0, 0);
            acc = __builtin_amdgcn_mfma_f32_32x32x16_bf16(al, bh, acc, 0, 0, 0);
            acc = __builtin_amdgcn_mfma_f32_32x32x16_bf16(ah, bl, acc, 0, 0, 0);
        }
    }
#undef LOADCHUNK

    // ---- partial out. C/D layout (m74/m101): col=lane&31, row=(reg&3)+8*(reg>>2)+4*(lane>>5)
    // Wave mq==kt holds exactly the rows THIS block reduces -> LDS bounce, no global.
    // Other waves store to P at AGENT scope (sc1 -> LLC, not HBM).
    __syncthreads();                                   // all waves done reading A LDS
    float* Lred = (float*)sm;                          // 32 x LREDP floats in A region
    {
        const int mb = mq * 32 + 4 * (lane >> 5);
        const int c0 = nh * 32 + m31;
        if (mq == kt) {                                // wave-uniform branch
            #pragma unroll
            for (int r = 0; r < 16; ++r) {
                int ml = 4 * (lane >> 5) + (r & 3) + 8 * (r >> 2);   // 0..31
                Lred[ml * LREDP + c0] = acc[r];
            }
        } else {
            float* Ps = P + (size_t)(kt * NT + nt) * (Bsz * 64);
            #pragma unroll
            for (int r = 0; r < 16; ++r) {
                int m = mb + (r & 3) + 8 * (r >> 2);
                float* p0 = Ps + m * 64 + c0;
                float v0 = acc[r];
                asm volatile("global_store_dword %0, %1, off sc1" :: "v"(p0), "v"(v0) : "memory");
            }
        }
    }
    asm volatile("s_waitcnt vmcnt(0)" ::: "memory");   // P drained to LLC

    // ---- stage next x slice (independent of P; normal stores, next-kernel visibility)
    if (t + 1 < Ssz && tid < 256) {
        int idx = bid * 256 + tid;                     // 65536 elems
        int bb = idx >> 9, ii = idx & 511;
        float xv = x[((size_t)bb * Ssz + (t + 1)) * Isz + ii];
        unsigned short xh = f2bf(xv);
        xthi_o[idx] = xh;
        xtlo_o[idx] = f2bf(xv - bf2f(xh));
    }

    __syncthreads();                                   // Lred visible + all waves' P drained

    // ---- ticket + spin: group = 4 kt-blocks of this nt; all blocks co-resident (grid=256=#CU)
    if (tid == 0) {
        unsigned* cp = &cnt[nt * 32];
        unsigned one = 1u;
        asm volatile("s_waitcnt vmcnt(0) lgkmcnt(0)" ::: "memory");
        asm volatile("global_atomic_add %0, %1, off sc1" :: "v"(cp), "v"(one) : "memory");
        const unsigned target = (unsigned)(KT * (t + 1));   // cumulative, no reset needed
        unsigned v;
        do {
            __builtin_amdgcn_s_sleep(1);
            asm volatile("global_load_dword %0, %1, off sc1\n\ts_waitcnt vmcnt(0)"
                         : "=v"(v) : "v"(cp) : "memory");
        } while (v < target);
    }
    __syncthreads();

    // ---- all 256 blocks reduce: block kt handles b in [kt*32, kt*32+32) of its nt cols
    {
        const int jl = tid & 15;                       // local hidden unit 0..15
        const int brow = kt * 32 + (tid >> 4);         // 32 b-rows per block
        const int j = nt * 16 + jl;
        const float* Pb = P + ((size_t)nt * Bsz + brow) * 64 + jl * 4;
        const size_t kstride = (size_t)NT * Bsz * 64;  // 524288 floats
        // three remote slices (skip own kt) at agent scope
        const int sA_ = (kt == 0) ? 1 : 0;
        const int sB_ = (kt <= 1) ? 2 : 1;
        const int sC_ = (kt <= 2) ? 3 : 2;
        f32x4 pA, pB, pC;
        GLOAD16_DEV(pA, Pb + (size_t)sA_ * kstride);
        GLOAD16_DEV(pB, Pb + (size_t)sB_ * kstride);
        GLOAD16_DEV(pC, Pb + (size_t)sC_ * kstride);
        f32x4 own = *(const f32x4*)&Lred[(tid >> 4) * LREDP + jl * 4];
        asm volatile("s_waitcnt vmcnt(0)" ::: "memory");
        __builtin_amdgcn_sched_barrier(0);
        f32x4 bp = *(const f32x4*)&biasP[(size_t)j * 4];
        float gf = bp.x + own[0] + pA[0] + pB[0] + pC[0];
        float gi = bp.y + own[1] + pA[1] + pB[1] + pC[1];
        float gg = bp.z + own[2] + pA[2] + pB[2] + pC[2];
        float go = bp.w + own[3] + pA[3] + pB[3] + pC[3];
        float f  = fsig(gf);
        float i_ = fsig(gi);
        float g  = ftanh(gg);
        float o  = fsig(go);
        size_t sidx = (size_t)brow * Hsz + j;
        float cn = f * c_st[sidx] + i_ * g;
        c_st[sidx] = cn;
        float hn = o * ftanh(cn);
        float hs = hsum[sidx] + hn;
        hsum[sidx] = hs;
        unsigned short hh = f2bf(hn);
        hhi_o[sidx] = hh;
        hlo_o[sidx] = f2bf(hn - bf2f(hh));
        if (t == Ssz - 1) out[sidx] = hs * (1.f / (float)Ssz);
    }
}

extern "C" void kernel_launch(void* const* d_in, const int* in_sizes, int n_in,
                              void* d_out, int out_size, void* d_ws, size_t ws_size,
                              hipStream_t stream) {
    const float* x    = (const float*)d_in[0];
    const float* W    = (const float*)d_in[1];
    const float* U    = (const float*)d_in[2];
    const float* bias = (const float*)d_in[3];
    float* out = (float*)d_out;

    unsigned char* base = (unsigned char*)d_ws;
    // ws carve (~36.3 MB total)
    unsigned short* WUthi = (unsigned short*)(base);                       // 12,582,912 B
    unsigned short* WUtlo = (unsigned short*)(base + 12582912);            // 12,582,912 B
    float*          P     = (float*)(base + 25165824);                     //  8,388,608 B
    float*          c_st  = (float*)(base + 33554432);                     //    524,288 B
    float*          hsum  = (float*)(base + 34078720);                     //    524,288 B
    unsigned short* hh0   = (unsigned short*)(base + 34603008);            //    262,144 B
    unsigned short* hl0   = (unsigned short*)(base + 34865152);            //    262,144 B
    unsigned short* hh1   = (unsigned short*)(base + 35127296);            //    262,144 B
    unsigned short* hl1   = (unsigned short*)(base + 35389440);            //    262,144 B
    unsigned short* xh0   = (unsigned short*)(base + 35651584);            //    131,072 B
    unsigned short* xl0   = (unsigned short*)(base + 35782656);            //    131,072 B
    unsigned short* xh1   = (unsigned short*)(base + 35913728);            //    131,072 B
    unsigned short* xl1   = (unsigned short*)(base + 36044800);            //    131,072 B
    float*          biasP = (float*)(base + 36175872);                     //     16,384 B
    unsigned*       cnt   = (unsigned*)(base + 36192256);                  //      8,192 B

    unsigned short* xh[2] = {xh0, xh1};
    unsigned short* xl[2] = {xl0, xl1};
    unsigned short* hh[2] = {hh0, hh1};
    unsigned short* hl[2] = {hl0, hl1};

    conv_wu<<<dim3(G4 / 32, Ktot / 32), 256, 0, stream>>>(W, U, WUthi, WUtlo);
    lstm_init<<<(Bsz * Hsz) / 256, 256, 0, stream>>>(x, bias, c_st, hsum,
                                                     hh0, hl0, xh0, xl0, biasP, cnt);

    for (int t = 0; t < Ssz; ++t) {
        lstm_step<<<NT * KT, 512, SMEM_ELEMS * 2, stream>>>(
            WUthi, WUtlo, xh[t & 1], xl[t & 1], hh[t & 1], hl[t & 1],
            biasP, x, t, c_st, hsum,
            hh[(t + 1) & 1], hl[(t + 1) & 1], xh[(t + 1) & 1], xl[(t + 1) & 1],
            P, cnt, out);
    }
}